// Round 3
// baseline (354.281 us; speedup 1.0000x reference)
//
#include <hip/hip_runtime.h>

// Problem constants (ConvHex): B=256, C_IN=64, C_OUT=128, H=1039, K=6
// Dtypes: x, weights, bias, out = fp32; neighbors = int32.
// Compute uses bf16 MFMA; threshold 3.375e-2 covers bf16 rounding (measured 7.8e-3).
//
// Design (round 3): one block per batch, 1024 threads (16 waves = 4/SIMD).
// x[b] is transposed straight into LDS (bf16, XOR-swizzled 128B rows, 1040
// rows = 130 KB), then all 17 h-tiles are computed from LDS in place via
// gathered ds_read_b128 (neighbors are batch-local). Wave = (m-pair, h-
// quarter): per k-step 1 gathered B-read feeds 2 MFMAs, so total LDS read
// volume matches the 8-wave version while 4 waves/SIMD hide latency.
#define BATCH 256
#define CIN   64
#define COUT  128
#define HEX   1039
#define KNB   6
#define ZROW  HEX              // zero row index in LDS (gather target for pads)
#define NTH   17               // ceil(HEX / 64) h-tiles
#define LDSB  ((HEX + 1) * 128)   // 1040 rows * 128 B = 133120 B

typedef __attribute__((ext_vector_type(8))) short bf16x8;   // 8 bf16 = 4 VGPRs
typedef __attribute__((ext_vector_type(4))) float f32x4;

__device__ __forceinline__ unsigned short f2bf(float f) {
    unsigned int u = __builtin_bit_cast(unsigned int, f);
    u += 0x7fffu + ((u >> 16) & 1);          // RTNE
    return (unsigned short)(u >> 16);
}

// ---------------------------------------------------------------------------
// k_prep: pack [Wc|Wn] fp32 -> wf bf16 in MFMA A-fragment lane order.
// wf element e = ((kb*8 + mt)*64 + lane)*8 + j :
//   o = mt*16 + (lane&15); kd = kb*32 + (lane>>4)*8 + j = jn*64 + c
__global__ __launch_bounds__(256) void k_prep(const float* __restrict__ wc,
                                              const float* __restrict__ wn,
                                              unsigned short* __restrict__ wf) {
    int e    = blockIdx.x * 256 + threadIdx.x;   // 0 .. 57343
    int j    = e & 7;
    int lane = (e >> 3) & 63;
    int mt   = (e >> 9) & 7;
    int kb   = e >> 12;                          // 0..13
    int o  = mt * 16 + (lane & 15);
    int kd = kb * 32 + (lane >> 4) * 8 + j;
    int jn = kd >> 6;
    int c  = kd & 63;
    float v = (jn == 0) ? wc[o * CIN + c]
                        : wn[(o * CIN + c) * KNB + (jn - 1)];
    wf[e] = f2bf(v);
}

// ---------------------------------------------------------------------------
// k_main: block = batch. 1024 threads = 16 waves = 4 m-pairs x 4 h-quarters.
// Phase 1: transpose x[b][c][h] -> LDS row h (64 bf16, swizzled chunks).
//   Row layout: byte(h, chunk q) = h*128 + ((q ^ (h&7))<<4). Rows are 128B =
//   exactly 32 banks, so the bank pattern depends only on the chunk slot; the
//   XOR keeps the phase-1 b128 writes bijective and the phase-2 gathered b128
//   reads (random rows -> near-uniform slots) bank-balanced.
// Phase 2: per tile ht, wave (m,hq) computes o in [32m,32m+32) x 16 h.
//   B-frags gathered from LDS by per-lane row index (center / nb / ZROW);
//   A-fragments from L1 (wf); 28 MFMA per wave per tile; no barriers.
__global__ __launch_bounds__(1024) void k_main(const float* __restrict__ x,
                                               const int* __restrict__ nb,
                                               const unsigned short* __restrict__ wf,
                                               const float* __restrict__ bias,
                                               float* __restrict__ out) {
    extern __shared__ __align__(16) unsigned short XT[];   // [1040 rows][128 B]

    int b    = blockIdx.x;
    int tid  = threadIdx.x;
    int lane = tid & 63;
    int wv   = tid >> 6;                 // 0..15
    int quad = lane >> 4;
    int l16  = lane & 15;
    int m    = wv & 3;                   // m-pair: o-tiles {2m, 2m+1}
    int hq   = wv >> 2;                  // h quarter 0..3

    // ---- A fragments: 28 frags (compiler may stream from L1 per tile).
    const bf16x8* wfv = (const bf16x8*)wf;
    bf16x8 A[14][2];
    #pragma unroll
    for (int kb = 0; kb < 14; ++kb)
        #pragma unroll
        for (int mi = 0; mi < 2; ++mi)
            A[kb][mi] = wfv[(kb * 8 + 2 * m + mi) * 64 + lane];

    float bs[2][4];
    #pragma unroll
    for (int mi = 0; mi < 2; ++mi)
        #pragma unroll
        for (int r = 0; r < 4; ++r)
            bs[mi][r] = bias[(2 * m + mi) * 16 + quad * 4 + r];

    // ---- phase 1: transpose into LDS. Task e = h*8 + cc (1040*8 = 8320).
    // Per task: 8 strided 4B loads (wave: 8 c-rows x 32B segments, each line
    // consumed once by the block) -> one swizzled b128 LDS write.
    {
        const float* xb = x + (size_t)b * (CIN * HEX);
        #pragma unroll 1
        for (int t = 0; t < 9; ++t) {
            int e = t * 1024 + tid;
            if (e < 8320) {
                int h  = e >> 3;
                int cc = e & 7;
                bf16x8 v = {};
                if (h < HEX) {
                    #pragma unroll
                    for (int k = 0; k < 8; ++k)
                        v[k] = (short)f2bf(xb[(size_t)(cc * 8 + k) * HEX + h]);
                }
                *(bf16x8*)((char*)XT + h * 128 + ((cc ^ (h & 7)) << 4)) = v;
            }
        }
    }
    __syncthreads();

    // ---- phase 2: 17 tiles, no barriers.
    int ho = hq * 16 + l16;                  // h = ht*64 + ho
    int rawn[6];                             // next tile's nb values
    int voff[7];                             // current tile's LDS byte offsets

    auto loadraw = [&](int ht2) {            // issue 6 nb loads for tile ht2
        int h  = ht2 * 64 + ho;
        int hs = (h < HEX) ? h : 0;
        #pragma unroll
        for (int j = 0; j < KNB; ++j)
            rawn[j] = nb[hs * KNB + j];
    };
    // byte offset of (row g, chunk quad) with swizzle; ks-odd XORs bit 6.
    auto offg = [&](int g) { return (g << 7) | ((quad ^ (g & 7)) << 4); };

    loadraw(0);
    float* outb = out + (size_t)b * ((size_t)COUT * HEX);

    #pragma unroll 1
    for (int ht = 0; ht < NTH; ++ht) {
        // finalize current tile from rawn (VALU only)
        int h  = ht * 64 + ho;
        bool hv = (h < HEX);
        voff[0] = offg(hv ? h : ZROW);
        int cnt = 1;
        #pragma unroll
        for (int j = 0; j < KNB; ++j) {
            int t2 = rawn[j];
            bool val = hv && (t2 >= 0);
            cnt += val ? 1 : 0;
            voff[j + 1] = offg(val ? t2 : ZROW);
        }
        float inv = 1.0f / (float)cnt;
        if (ht + 1 < NTH) loadraw(ht + 1);   // prefetch next tile's indices

        f32x4 acc[2] = {};                   // [mi]
        #pragma unroll
        for (int ks = 0; ks < 14; ++ks) {
            int jn = ks >> 1;
            int xr = (ks & 1) << 6;          // odd ks: chunk slot +4 (XOR bit 6)
            bf16x8 bb = *(const bf16x8*)((const char*)XT + (voff[jn] ^ xr));
            acc[0] = __builtin_amdgcn_mfma_f32_16x16x32_bf16(A[ks][0], bb, acc[0], 0, 0, 0);
            acc[1] = __builtin_amdgcn_mfma_f32_16x16x32_bf16(A[ks][1], bb, acc[1], 0, 0, 0);
        }

        // epilogue: D col = l16 (h), row = quad*4 + r (o within 16-tile)
        if (hv) {
            #pragma unroll
            for (int mi = 0; mi < 2; ++mi)
                #pragma unroll
                for (int r = 0; r < 4; ++r) {
                    int o = (2 * m + mi) * 16 + quad * 4 + r;
                    outb[(size_t)o * HEX + h] = acc[mi][r] * inv + bs[mi][r];
                }
        }
    }
}

// ---------------------------------------------------------------------------
extern "C" void kernel_launch(void* const* d_in, const int* in_sizes, int n_in,
                              void* d_out, int out_size, void* d_ws, size_t ws_size,
                              hipStream_t stream) {
    const float* x    = (const float*)d_in[0];   // [256][64][1039] fp32
    const int*   nb   = (const int*)d_in[1];     // [1039][6] int32
    const float* wc   = (const float*)d_in[2];   // [128][64] fp32
    const float* wn   = (const float*)d_in[3];   // [128][64][6] fp32
    const float* bias = (const float*)d_in[4];   // [128] fp32
    float*       out  = (float*)d_out;           // [256][128][1039] fp32

    unsigned short* wf = (unsigned short*)d_ws;  // 114688 B of workspace

    static bool s_attr_done = false;
    if (!s_attr_done) {                          // host-side, graph-safe, once
        hipFuncSetAttribute((const void*)k_main,
                            hipFuncAttributeMaxDynamicSharedMemorySize, LDSB);
        s_attr_done = true;
    }

    hipLaunchKernelGGL(k_prep, dim3(224),   dim3(256),  0,    stream, wc, wn, wf);
    hipLaunchKernelGGL(k_main, dim3(BATCH), dim3(1024), LDSB, stream,
                       x, nb, wf, bias, out);
}

// Round 4
// 221.274 us; speedup vs baseline: 1.6011x; 1.6011x over previous
//
#include <hip/hip_runtime.h>

// Problem constants (ConvHex): B=256, C_IN=64, C_OUT=128, H=1039, K=6
// Dtypes: x, weights, bias, out = fp32; neighbors = int32.
// Compute uses bf16 MFMA; threshold 3.375e-2 covers bf16 rounding (measured 7.8e-3).
//
// Design (round 4): one block per batch, 768 threads (12 waves = 3/SIMD;
// VGPR cap 170 holds the 112-reg A file -- round 3's 1024-thr/128-cap spilled).
// x[b] is transposed straight into LDS (bf16, XOR-swizzled 128B rows, 1040
// rows = 130 KB), then 22 48-h tiles are computed from LDS in place via
// gathered ds_read_b128 (neighbors are batch-local). Wave = (m-pair, h16):
// per k-step 1 gathered B-read feeds 2 MFMAs, so per-CU LDS read volume
// matches the 512-thr version while 3 waves/SIMD hide latency.
#define BATCH 256
#define CIN   64
#define COUT  128
#define HEX   1039
#define KNB   6
#define ZROW  HEX              // zero row index in LDS (gather target for pads)
#define TILEH 48               // h per tile (12 waves = 4 m-pairs x 3 h16s)
#define NTILE 22               // ceil(HEX / TILEH)
#define LDSB  ((HEX + 1) * 128)   // 1040 rows * 128 B = 133120 B

typedef __attribute__((ext_vector_type(8))) short bf16x8;   // 8 bf16 = 4 VGPRs
typedef __attribute__((ext_vector_type(4))) float f32x4;

__device__ __forceinline__ unsigned short f2bf(float f) {
    unsigned int u = __builtin_bit_cast(unsigned int, f);
    u += 0x7fffu + ((u >> 16) & 1);          // RTNE
    return (unsigned short)(u >> 16);
}

// ---------------------------------------------------------------------------
// k_prep: pack [Wc|Wn] fp32 -> wf bf16 in MFMA A-fragment lane order.
// wf element e = ((kb*8 + mt)*64 + lane)*8 + j :
//   o = mt*16 + (lane&15); kd = kb*32 + (lane>>4)*8 + j = jn*64 + c
__global__ __launch_bounds__(256) void k_prep(const float* __restrict__ wc,
                                              const float* __restrict__ wn,
                                              unsigned short* __restrict__ wf) {
    int e    = blockIdx.x * 256 + threadIdx.x;   // 0 .. 57343
    int j    = e & 7;
    int lane = (e >> 3) & 63;
    int mt   = (e >> 9) & 7;
    int kb   = e >> 12;                          // 0..13
    int o  = mt * 16 + (lane & 15);
    int kd = kb * 32 + (lane >> 4) * 8 + j;
    int jn = kd >> 6;
    int c  = kd & 63;
    float v = (jn == 0) ? wc[o * CIN + c]
                        : wn[(o * CIN + c) * KNB + (jn - 1)];
    wf[e] = f2bf(v);
}

// ---------------------------------------------------------------------------
// k_main: block = batch. 768 threads = 12 waves = 4 m-pairs x 3 h16s.
// Phase 1: transpose x[b][c][h] -> LDS row h (64 bf16, swizzled chunks).
//   Row layout: byte(h, chunk q) = h*128 + ((q ^ (h&7))<<4). Rows are 128B =
//   exactly 32 banks, so the bank pattern depends only on the chunk slot; the
//   XOR keeps the phase-1 b128 writes bijective and the phase-2 gathered b128
//   reads (random rows -> near-uniform slots) bank-balanced.
// Phase 2: per tile ht, wave (m,hq) computes o in [32m,32m+32) x 16 h.
//   B-frags gathered from LDS by per-lane row index (center / nb / ZROW);
//   A-fragments persistent in registers; 28 MFMA per wave per tile; no
//   barriers after the single post-transpose one.
__global__ __launch_bounds__(768) void k_main(const float* __restrict__ x,
                                              const int* __restrict__ nb,
                                              const unsigned short* __restrict__ wf,
                                              const float* __restrict__ bias,
                                              float* __restrict__ out) {
    extern __shared__ __align__(16) unsigned short XT[];   // [1040 rows][128 B]

    int b    = blockIdx.x;
    int tid  = threadIdx.x;
    int lane = tid & 63;
    int wv   = tid >> 6;                 // 0..11
    int quad = lane >> 4;
    int l16  = lane & 15;
    int m    = wv & 3;                   // m-pair: o-tiles {2m, 2m+1}
    int hq   = wv >> 2;                  // h sixteenth 0..2

    // ---- A fragments: 28 frags = 112 VGPR, loaded once (issue early,
    // latency hidden under the phase-1 transpose).
    const bf16x8* wfv = (const bf16x8*)wf;
    bf16x8 A[14][2];
    #pragma unroll
    for (int kb = 0; kb < 14; ++kb)
        #pragma unroll
        for (int mi = 0; mi < 2; ++mi)
            A[kb][mi] = wfv[(kb * 8 + 2 * m + mi) * 64 + lane];

    float bs[2][4];
    #pragma unroll
    for (int mi = 0; mi < 2; ++mi)
        #pragma unroll
        for (int r = 0; r < 4; ++r)
            bs[mi][r] = bias[(2 * m + mi) * 16 + quad * 4 + r];

    // ---- phase 1: transpose into LDS. Task e = h*8 + cc (1040*8 = 8320).
    // Per task: 8 strided 4B loads (wave: 8 c-rows x 32B segments, each line
    // consumed once by the block) -> one swizzled b128 LDS write.
    {
        const float* xb = x + (size_t)b * (CIN * HEX);
        #pragma unroll 1
        for (int t = 0; t < 11; ++t) {
            int e = t * 768 + tid;
            if (e < 8320) {
                int h  = e >> 3;
                int cc = e & 7;
                bf16x8 v = {};
                if (h < HEX) {
                    #pragma unroll
                    for (int k = 0; k < 8; ++k)
                        v[k] = (short)f2bf(xb[(size_t)(cc * 8 + k) * HEX + h]);
                }
                *(bf16x8*)((char*)XT + h * 128 + ((cc ^ (h & 7)) << 4)) = v;
            }
        }
    }
    __syncthreads();

    // ---- phase 2: 22 tiles, no barriers.
    int ho = hq * 16 + l16;                  // h = ht*TILEH + ho
    int rawn[6];                             // next tile's nb values
    int voff[7];                             // current tile's LDS byte offsets

    auto loadraw = [&](int ht2) {            // issue 6 nb loads for tile ht2
        int h  = ht2 * TILEH + ho;
        int hs = (h < HEX) ? h : 0;
        #pragma unroll
        for (int j = 0; j < KNB; ++j)
            rawn[j] = nb[hs * KNB + j];
    };
    // byte offset of (row g, chunk quad) with swizzle; ks-odd XORs bit 6.
    auto offg = [&](int g) { return (g << 7) | ((quad ^ (g & 7)) << 4); };

    loadraw(0);
    float* outb = out + (size_t)b * ((size_t)COUT * HEX);

    #pragma unroll 1
    for (int ht = 0; ht < NTILE; ++ht) {
        // finalize current tile from rawn (VALU only)
        int h  = ht * TILEH + ho;
        bool hv = (h < HEX);
        voff[0] = offg(hv ? h : ZROW);
        int cnt = 1;
        #pragma unroll
        for (int j = 0; j < KNB; ++j) {
            int t2 = rawn[j];
            bool val = hv && (t2 >= 0);
            cnt += val ? 1 : 0;
            voff[j + 1] = offg(val ? t2 : ZROW);
        }
        float inv = 1.0f / (float)cnt;
        if (ht + 1 < NTILE) loadraw(ht + 1);   // prefetch next tile's indices

        f32x4 acc[2] = {};                   // [mi]
        #pragma unroll
        for (int ks = 0; ks < 14; ++ks) {
            int jn = ks >> 1;
            int xr = (ks & 1) << 6;          // odd ks: chunk slot +4 (XOR bit 6)
            bf16x8 bb = *(const bf16x8*)((const char*)XT + (voff[jn] ^ xr));
            acc[0] = __builtin_amdgcn_mfma_f32_16x16x32_bf16(A[ks][0], bb, acc[0], 0, 0, 0);
            acc[1] = __builtin_amdgcn_mfma_f32_16x16x32_bf16(A[ks][1], bb, acc[1], 0, 0, 0);
        }

        // epilogue: D col = l16 (h), row = quad*4 + r (o within 16-tile)
        if (hv) {
            #pragma unroll
            for (int mi = 0; mi < 2; ++mi)
                #pragma unroll
                for (int r = 0; r < 4; ++r) {
                    int o = (2 * m + mi) * 16 + quad * 4 + r;
                    outb[(size_t)o * HEX + h] = acc[mi][r] * inv + bs[mi][r];
                }
        }
    }
}

// ---------------------------------------------------------------------------
extern "C" void kernel_launch(void* const* d_in, const int* in_sizes, int n_in,
                              void* d_out, int out_size, void* d_ws, size_t ws_size,
                              hipStream_t stream) {
    const float* x    = (const float*)d_in[0];   // [256][64][1039] fp32
    const int*   nb   = (const int*)d_in[1];     // [1039][6] int32
    const float* wc   = (const float*)d_in[2];   // [128][64] fp32
    const float* wn   = (const float*)d_in[3];   // [128][64][6] fp32
    const float* bias = (const float*)d_in[4];   // [128] fp32
    float*       out  = (float*)d_out;           // [256][128][1039] fp32

    unsigned short* wf = (unsigned short*)d_ws;  // 114688 B of workspace

    static bool s_attr_done = false;
    if (!s_attr_done) {                          // host-side, graph-safe, once
        hipFuncSetAttribute((const void*)k_main,
                            hipFuncAttributeMaxDynamicSharedMemorySize, LDSB);
        s_attr_done = true;
    }

    hipLaunchKernelGGL(k_prep, dim3(224),   dim3(256), 0,    stream, wc, wn, wf);
    hipLaunchKernelGGL(k_main, dim3(BATCH), dim3(768), LDSB, stream,
                       x, nb, wf, bias, out);
}